// Round 1
// baseline (862.403 us; speedup 1.0000x reference)
//
#include <hip/hip_runtime.h>
#include <hip/hip_bf16.h>
#include <math.h>

#define N_NODES 12288
#define N_EDGES 196608
#define EP_EDGES (N_EDGES + N_NODES)   // 208896 edges incl. self loops
#define HEADS 4
#define HID 256
#define FDIM 1024                      // HEADS*HID
#define EMB 16
#define NEG_SLOPE 0.2f

// ---------------- CSR build (dst-sorted, reused for all 3 layers) ----------------
__global__ void k_hist(const int* __restrict__ ei, int* __restrict__ cnt) {
  int i = blockIdx.x * 256 + threadIdx.x;
  if (i >= EP_EDGES) return;
  int d = (i < N_EDGES) ? ei[N_EDGES + i] : (i - N_EDGES);
  atomicAdd(&cnt[d], 1);
}

__global__ __launch_bounds__(1024) void k_scan(const int* __restrict__ cnt, int* __restrict__ row_ptr) {
  __shared__ int sd[1024];
  __shared__ int s_off;
  int tid = threadIdx.x;
  if (tid == 0) s_off = 0;
  __syncthreads();
  for (int base = 0; base < N_NODES; base += 1024) {
    int v = cnt[base + tid];
    sd[tid] = v;
    __syncthreads();
    for (int d = 1; d < 1024; d <<= 1) {
      int t = (tid >= d) ? sd[tid - d] : 0;
      __syncthreads();
      sd[tid] += t;
      __syncthreads();
    }
    int off = s_off;
    row_ptr[base + tid] = off + sd[tid] - v;   // exclusive scan
    __syncthreads();
    if (tid == 1023) s_off = off + sd[1023];
    __syncthreads();
  }
  if (tid == 0) row_ptr[N_NODES] = s_off;
}

__global__ void k_scatter(const int* __restrict__ ei, const int* __restrict__ row_ptr,
                          int* __restrict__ cur, int* __restrict__ csr_src) {
  int i = blockIdx.x * 256 + threadIdx.x;
  if (i >= EP_EDGES) return;
  int s, d;
  if (i < N_EDGES) { s = ei[i]; d = ei[N_EDGES + i]; }
  else             { s = i - N_EDGES; d = s; }
  int pos = row_ptr[d] + atomicAdd(&cur[d], 1);
  csr_src[pos] = s;
}

// ---------------- fp32 GEMM: C[M,N] = A[M,K] @ B[K,N]; M%128==0, N%128==0, K%8==0 ----
__global__ __launch_bounds__(256) void k_gemm(const float* __restrict__ A, const float* __restrict__ B,
                                              float* __restrict__ C, int M, int N, int K) {
  __shared__ float As[8][128];
  __shared__ float Bs[8][128];
  const int tid = threadIdx.x;
  const int tx = tid & 15, ty = tid >> 4;
  const int row0 = blockIdx.y * 128, col0 = blockIdx.x * 128;
  const int mA = tid >> 1, kA = (tid & 1) * 4;
  const int kB = tid >> 5, nB = (tid & 31) * 4;
  float acc[8][8] = {};
  for (int k0 = 0; k0 < K; k0 += 8) {
    float4 av = *reinterpret_cast<const float4*>(&A[(size_t)(row0 + mA) * K + k0 + kA]);
    float4 bv = *reinterpret_cast<const float4*>(&B[(size_t)(k0 + kB) * N + col0 + nB]);
    As[kA + 0][mA] = av.x; As[kA + 1][mA] = av.y; As[kA + 2][mA] = av.z; As[kA + 3][mA] = av.w;
    *reinterpret_cast<float4*>(&Bs[kB][nB]) = bv;
    __syncthreads();
#pragma unroll
    for (int k = 0; k < 8; ++k) {
      float a[8], b[8];
      *reinterpret_cast<float4*>(&a[0]) = *reinterpret_cast<const float4*>(&As[k][ty * 8]);
      *reinterpret_cast<float4*>(&a[4]) = *reinterpret_cast<const float4*>(&As[k][ty * 8 + 4]);
      *reinterpret_cast<float4*>(&b[0]) = *reinterpret_cast<const float4*>(&Bs[k][tx * 8]);
      *reinterpret_cast<float4*>(&b[4]) = *reinterpret_cast<const float4*>(&Bs[k][tx * 8 + 4]);
#pragma unroll
      for (int i = 0; i < 8; ++i)
#pragma unroll
        for (int j = 0; j < 8; ++j) acc[i][j] = fmaf(a[i], b[j], acc[i][j]);
    }
    __syncthreads();
  }
  for (int i = 0; i < 8; ++i) {
    size_t r = (size_t)(row0 + ty * 8 + i) * N + col0 + tx * 8;
    *reinterpret_cast<float4*>(&C[r])     = make_float4(acc[i][0], acc[i][1], acc[i][2], acc[i][3]);
    *reinterpret_cast<float4*>(&C[r + 4]) = make_float4(acc[i][4], acc[i][5], acc[i][6], acc[i][7]);
  }
}

// ---------------- attention coefficients: alpha_src/dst[n,h] = dot(h[n,h,:], a[h,:]) ----
__global__ __launch_bounds__(256) void k_alpha4(const float* __restrict__ h, const float* __restrict__ a_s,
                                                const float* __restrict__ a_d,
                                                float* __restrict__ asrc, float* __restrict__ adst) {
  int wid = (blockIdx.x * 256 + threadIdx.x) >> 6;   // node*4 + head
  int lane = threadIdx.x & 63;
  int node = wid >> 2, hd = wid & 3;
  float4 hv = *reinterpret_cast<const float4*>(&h[(size_t)node * FDIM + hd * HID + lane * 4]);
  float4 sv = *reinterpret_cast<const float4*>(&a_s[hd * HID + lane * 4]);
  float4 dv = *reinterpret_cast<const float4*>(&a_d[hd * HID + lane * 4]);
  float ps = hv.x * sv.x + hv.y * sv.y + hv.z * sv.z + hv.w * sv.w;
  float pd = hv.x * dv.x + hv.y * dv.y + hv.z * dv.z + hv.w * dv.w;
  for (int off = 32; off > 0; off >>= 1) {
    ps += __shfl_down(ps, off);
    pd += __shfl_down(pd, off);
  }
  if (lane == 0) { asrc[wid] = ps; adst[wid] = pd; }
}

// ---------------- GAT aggregation, H=4, F=256: one wave per (node, head) -------------
template <bool DO_ELU>
__global__ __launch_bounds__(256) void k_agg4(const float* __restrict__ h, const float* __restrict__ asrc,
                                              const float* __restrict__ adst, const int* __restrict__ row_ptr,
                                              const int* __restrict__ csr_src, const float* __restrict__ bias,
                                              float* __restrict__ out) {
  int wid = (blockIdx.x * 256 + threadIdx.x) >> 6;
  int lane = threadIdx.x & 63;
  int node = wid >> 2, hd = wid & 3;
  int beg = row_ptr[node], end = row_ptr[node + 1];
  float adn = adst[wid];
  float m = -INFINITY, s = 0.f;
  float ax = 0.f, ay = 0.f, az = 0.f, aw = 0.f;
  for (int e = beg; e < end; ++e) {
    int sidx = csr_src[e];
    float a = asrc[sidx * 4 + hd] + adn;
    a = a > 0.f ? a : NEG_SLOPE * a;            // leaky_relu
    float nm = fmaxf(m, a);
    float sc = __expf(m - nm);                  // exp(-inf)=0 on first edge
    float p  = __expf(a - nm);
    m = nm;
    s = s * sc + p;
    float4 hv = *reinterpret_cast<const float4*>(&h[(size_t)sidx * FDIM + hd * HID + lane * 4]);
    ax = ax * sc + p * hv.x;
    ay = ay * sc + p * hv.y;
    az = az * sc + p * hv.z;
    aw = aw * sc + p * hv.w;
  }
  float inv = 1.f / s;
  int fo = hd * HID + lane * 4;
  float4 bv = *reinterpret_cast<const float4*>(&bias[fo]);
  float4 o;
  o.x = ax * inv + bv.x; o.y = ay * inv + bv.y; o.z = az * inv + bv.z; o.w = aw * inv + bv.w;
  if (DO_ELU) {
    o.x = o.x > 0.f ? o.x : __expf(o.x) - 1.f;
    o.y = o.y > 0.f ? o.y : __expf(o.y) - 1.f;
    o.z = o.z > 0.f ? o.z : __expf(o.z) - 1.f;
    o.w = o.w > 0.f ? o.w : __expf(o.w) - 1.f;
  }
  *reinterpret_cast<float4*>(&out[(size_t)node * FDIM + fo]) = o;
}

// ---------------- layer-3 GEMM: [N,1024] @ [1024,16], B cached in LDS ----------------
__global__ __launch_bounds__(256) void k_gemm_n16(const float* __restrict__ A, const float* __restrict__ B,
                                                  float* __restrict__ C, int K) {
  __shared__ float Bs[16384];                   // 1024 x 16 = full B
  int tid = threadIdx.x;
  for (int idx = tid * 4; idx < K * 16; idx += 1024)
    *reinterpret_cast<float4*>(&Bs[idx]) = *reinterpret_cast<const float4*>(&B[idx]);
  __syncthreads();
  int row = blockIdx.x * 16 + (tid >> 4);
  int col = tid & 15;
  const float* Ar = &A[(size_t)row * K];
  float acc = 0.f;
  for (int k = 0; k < K; k += 4) {
    float4 av = *reinterpret_cast<const float4*>(&Ar[k]);
    acc = fmaf(av.x, Bs[(k + 0) * 16 + col],
          fmaf(av.y, Bs[(k + 1) * 16 + col],
          fmaf(av.z, Bs[(k + 2) * 16 + col],
          fmaf(av.w, Bs[(k + 3) * 16 + col], acc))));
  }
  C[(size_t)row * 16 + col] = acc;
}

__global__ void k_alpha1(const float* __restrict__ h3, const float* __restrict__ a_s,
                         const float* __restrict__ a_d, float* __restrict__ asrc,
                         float* __restrict__ adst) {
  int i = blockIdx.x * 256 + threadIdx.x;
  if (i >= N_NODES) return;
  float ps = 0.f, pd = 0.f;
#pragma unroll
  for (int j = 0; j < EMB; ++j) {
    float v = h3[i * EMB + j];
    ps += v * a_s[j];
    pd += v * a_d[j];
  }
  asrc[i] = ps;
  adst[i] = pd;
}

// layer-3 aggregation: 16 threads per node (one per feature), no ELU, writes z
__global__ __launch_bounds__(256) void k_agg1(const float* __restrict__ h3, const float* __restrict__ asrc,
                                              const float* __restrict__ adst, const int* __restrict__ row_ptr,
                                              const int* __restrict__ csr_src, const float* __restrict__ bias,
                                              float* __restrict__ z) {
  int idx = blockIdx.x * 256 + threadIdx.x;
  int node = idx >> 4, f = idx & 15;
  if (node >= N_NODES) return;
  int beg = row_ptr[node], end = row_ptr[node + 1];
  float adn = adst[node];
  float m = -INFINITY, s = 0.f, acc = 0.f;
  for (int e = beg; e < end; ++e) {
    int sidx = csr_src[e];
    float a = asrc[sidx] + adn;
    a = a > 0.f ? a : NEG_SLOPE * a;
    float nm = fmaxf(m, a);
    float sc = __expf(m - nm);
    float p  = __expf(a - nm);
    m = nm;
    s = s * sc + p;
    acc = acc * sc + p * h3[sidx * EMB + f];
  }
  z[node * EMB + f] = acc / s + bias[f];
}

// ---------------- adjacency reconstruction: sigmoid(z @ z^T), 64x64 tiles -----------
__global__ __launch_bounds__(256) void k_adj(const float* __restrict__ z, float* __restrict__ adj) {
  __shared__ float Zr[16][64];   // k-major
  __shared__ float Zc[16][64];
  int tid = threadIdx.x;
  int r0 = blockIdx.y * 64, c0 = blockIdx.x * 64;
  {
    int m = tid >> 2, kk = (tid & 3) * 4;
    float4 v = *reinterpret_cast<const float4*>(&z[(size_t)(r0 + m) * EMB + kk]);
    Zr[kk + 0][m] = v.x; Zr[kk + 1][m] = v.y; Zr[kk + 2][m] = v.z; Zr[kk + 3][m] = v.w;
    float4 w = *reinterpret_cast<const float4*>(&z[(size_t)(c0 + m) * EMB + kk]);
    Zc[kk + 0][m] = w.x; Zc[kk + 1][m] = w.y; Zc[kk + 2][m] = w.z; Zc[kk + 3][m] = w.w;
  }
  __syncthreads();
  int tx = tid & 15, ty = tid >> 4;
  float acc[4][4] = {};
#pragma unroll
  for (int k = 0; k < 16; ++k) {
    float a[4], b[4];
#pragma unroll
    for (int i = 0; i < 4; ++i) a[i] = Zr[k][ty * 4 + i];
#pragma unroll
    for (int j = 0; j < 4; ++j) b[j] = Zc[k][tx * 4 + j];
#pragma unroll
    for (int i = 0; i < 4; ++i)
#pragma unroll
      for (int j = 0; j < 4; ++j) acc[i][j] = fmaf(a[i], b[j], acc[i][j]);
  }
  for (int i = 0; i < 4; ++i) {
    float4 o;
    o.x = 1.f / (1.f + __expf(-acc[i][0]));
    o.y = 1.f / (1.f + __expf(-acc[i][1]));
    o.z = 1.f / (1.f + __expf(-acc[i][2]));
    o.w = 1.f / (1.f + __expf(-acc[i][3]));
    *reinterpret_cast<float4*>(&adj[(size_t)(r0 + ty * 4 + i) * N_NODES + c0 + tx * 4]) = o;
  }
}

// ---------------- Student-t soft assignment, K=2 ------------------------------------
__global__ void k_q(const float* __restrict__ z, const float* __restrict__ centers,
                    float* __restrict__ q) {
  int i = blockIdx.x * 256 + threadIdx.x;
  if (i >= N_NODES) return;
  float zz[EMB];
#pragma unroll
  for (int j = 0; j < EMB; ++j) zz[j] = z[i * EMB + j];
  float q0, q1;
  {
    float d2 = 0.f;
#pragma unroll
    for (int j = 0; j < EMB; ++j) { float d = zz[j] - centers[j]; d2 = fmaf(d, d, d2); }
    q0 = 1.f / (1.f + d2);
  }
  {
    float d2 = 0.f;
#pragma unroll
    for (int j = 0; j < EMB; ++j) { float d = zz[j] - centers[EMB + j]; d2 = fmaf(d, d, d2); }
    q1 = 1.f / (1.f + d2);
  }
  float inv = 1.f / (q0 + q1);
  q[i * 2 + 0] = q0 * inv;
  q[i * 2 + 1] = q1 * inv;
}

// ====================================================================================
extern "C" void kernel_launch(void* const* d_in, const int* in_sizes, int n_in,
                              void* d_out, int out_size, void* d_ws, size_t ws_size,
                              hipStream_t stream) {
  const float* x   = (const float*)d_in[0];
  const int*   ei  = (const int*)d_in[1];
  const float* W1  = (const float*)d_in[2];
  const float* as1 = (const float*)d_in[3];
  const float* ad1 = (const float*)d_in[4];
  const float* b1  = (const float*)d_in[5];
  const float* W2  = (const float*)d_in[6];
  const float* as2 = (const float*)d_in[7];
  const float* ad2 = (const float*)d_in[8];
  const float* b2  = (const float*)d_in[9];
  const float* W3  = (const float*)d_in[10];
  const float* as3 = (const float*)d_in[11];
  const float* ad3 = (const float*)d_in[12];
  const float* b3  = (const float*)d_in[13];
  const float* centers = (const float*)d_in[14];
  float* out = (float*)d_out;

  char* ws = (char*)d_ws;
  size_t off = 0;
  auto alloc = [&](size_t bytes) { void* p = ws + off; off = (off + bytes + 255) & ~(size_t)255; return p; };
  int* cnt       = (int*)alloc((size_t)N_NODES * 4);
  int* cur       = (int*)alloc((size_t)N_NODES * 4);
  int* row_ptr   = (int*)alloc((size_t)(N_NODES + 1) * 4);
  int* csr_src   = (int*)alloc((size_t)EP_EDGES * 4);
  float* asrcA   = (float*)alloc((size_t)N_NODES * HEADS * 4);
  float* adstA   = (float*)alloc((size_t)N_NODES * HEADS * 4);
  float* asrc3   = (float*)alloc((size_t)N_NODES * 4);
  float* adst3   = (float*)alloc((size_t)N_NODES * 4);
  float* bufH    = (float*)alloc((size_t)N_NODES * FDIM * 4);
  float* bufAgg  = (float*)alloc((size_t)N_NODES * FDIM * 4);
  float* bufZ    = (float*)alloc((size_t)N_NODES * EMB * 4);

  hipMemsetAsync(cnt, 0, (size_t)N_NODES * 4, stream);
  hipMemsetAsync(cur, 0, (size_t)N_NODES * 4, stream);

  const int ep_blocks = (EP_EDGES + 255) / 256;
  k_hist<<<dim3(ep_blocks), dim3(256), 0, stream>>>(ei, cnt);
  k_scan<<<dim3(1), dim3(1024), 0, stream>>>(cnt, row_ptr);
  k_scatter<<<dim3(ep_blocks), dim3(256), 0, stream>>>(ei, row_ptr, cur, csr_src);

  // ---- layer 1: 128 -> 4x256
  k_gemm<<<dim3(FDIM / 128, N_NODES / 128), dim3(256), 0, stream>>>(x, W1, bufH, N_NODES, FDIM, 128);
  k_alpha4<<<dim3(N_NODES), dim3(256), 0, stream>>>(bufH, as1, ad1, asrcA, adstA);
  k_agg4<true><<<dim3(N_NODES), dim3(256), 0, stream>>>(bufH, asrcA, adstA, row_ptr, csr_src, b1, bufAgg);

  // ---- layer 2: 1024 -> 4x256
  k_gemm<<<dim3(FDIM / 128, N_NODES / 128), dim3(256), 0, stream>>>(bufAgg, W2, bufH, N_NODES, FDIM, FDIM);
  k_alpha4<<<dim3(N_NODES), dim3(256), 0, stream>>>(bufH, as2, ad2, asrcA, adstA);
  k_agg4<true><<<dim3(N_NODES), dim3(256), 0, stream>>>(bufH, asrcA, adstA, row_ptr, csr_src, b2, bufAgg);

  // ---- layer 3: 1024 -> 16, 1 head, no ELU; z written straight into d_out
  k_gemm_n16<<<dim3(N_NODES / 16), dim3(256), 0, stream>>>(bufAgg, W3, bufZ, FDIM);
  k_alpha1<<<dim3((N_NODES + 255) / 256), dim3(256), 0, stream>>>(bufZ, as3, ad3, asrc3, adst3);
  k_agg1<<<dim3(N_NODES * EMB / 256), dim3(256), 0, stream>>>(bufZ, asrc3, adst3, row_ptr, csr_src, b3, out);

  // ---- decoder
  float* adj = out + (size_t)N_NODES * EMB;
  float* q   = adj + (size_t)N_NODES * N_NODES;
  k_adj<<<dim3(N_NODES / 64, N_NODES / 64), dim3(256), 0, stream>>>(out, adj);
  k_q<<<dim3((N_NODES + 255) / 256), dim3(256), 0, stream>>>(out, centers, q);
}

// Round 2
// 639.220 us; speedup vs baseline: 1.3491x; 1.3491x over previous
//
#include <hip/hip_runtime.h>
#include <hip/hip_bf16.h>
#include <math.h>

#define N_NODES 12288
#define N_EDGES 196608
#define EP_EDGES (N_EDGES + N_NODES)   // 208896 edges incl. self loops
#define HEADS 4
#define HID 256
#define FDIM 1024                      // HEADS*HID
#define EMB 16
#define NEG_SLOPE 0.2f

typedef __attribute__((ext_vector_type(8))) short short8;
typedef __attribute__((ext_vector_type(4))) float f32x4;

// bf16 helpers (RNE)
__device__ __forceinline__ unsigned short f2bf(float f) {
  unsigned int u = __float_as_uint(f);
  u = (u + 0x7FFFu + ((u >> 16) & 1u)) >> 16;
  return (unsigned short)u;
}
__device__ __forceinline__ float bf2f(unsigned short h) {
  return __uint_as_float(((unsigned int)h) << 16);
}

// ---------------- CSR build (dst-sorted, reused for all 3 layers) ----------------
__global__ void k_hist(const int* __restrict__ ei, int* __restrict__ cnt) {
  int i = blockIdx.x * 256 + threadIdx.x;
  if (i >= EP_EDGES) return;
  int d = (i < N_EDGES) ? ei[N_EDGES + i] : (i - N_EDGES);
  atomicAdd(&cnt[d], 1);
}

__global__ __launch_bounds__(1024) void k_scan(const int* __restrict__ cnt, int* __restrict__ row_ptr) {
  __shared__ int sd[1024];
  __shared__ int s_off;
  int tid = threadIdx.x;
  if (tid == 0) s_off = 0;
  __syncthreads();
  for (int base = 0; base < N_NODES; base += 1024) {
    int v = cnt[base + tid];
    sd[tid] = v;
    __syncthreads();
    for (int d = 1; d < 1024; d <<= 1) {
      int t = (tid >= d) ? sd[tid - d] : 0;
      __syncthreads();
      sd[tid] += t;
      __syncthreads();
    }
    int off = s_off;
    row_ptr[base + tid] = off + sd[tid] - v;   // exclusive scan
    __syncthreads();
    if (tid == 1023) s_off = off + sd[1023];
    __syncthreads();
  }
  if (tid == 0) row_ptr[N_NODES] = s_off;
}

__global__ void k_scatter(const int* __restrict__ ei, const int* __restrict__ row_ptr,
                          int* __restrict__ cur, int* __restrict__ csr_src) {
  int i = blockIdx.x * 256 + threadIdx.x;
  if (i >= EP_EDGES) return;
  int s, d;
  if (i < N_EDGES) { s = ei[i]; d = ei[N_EDGES + i]; }
  else             { s = i - N_EDGES; d = s; }
  int pos = row_ptr[d] + atomicAdd(&cur[d], 1);
  csr_src[pos] = s;
}

// ---------------- fp32 -> bf16 hi/lo split (elementwise, no transpose) ---------------
__global__ void k_split(const float* __restrict__ in, unsigned short* __restrict__ hi,
                        unsigned short* __restrict__ lo, int n4) {
  int i = blockIdx.x * 256 + threadIdx.x;
  if (i >= n4) return;
  float4 v = *reinterpret_cast<const float4*>(&in[(size_t)i * 4]);
  ushort4 h, l;
  h.x = f2bf(v.x); l.x = f2bf(v.x - bf2f(h.x));
  h.y = f2bf(v.y); l.y = f2bf(v.y - bf2f(h.y));
  h.z = f2bf(v.z); l.z = f2bf(v.z - bf2f(h.z));
  h.w = f2bf(v.w); l.w = f2bf(v.w - bf2f(h.w));
  *reinterpret_cast<ushort4*>(&hi[(size_t)i * 4]) = h;
  *reinterpret_cast<ushort4*>(&lo[(size_t)i * 4]) = l;
}

// ---------------- transpose + split: W[K,N] f32 -> Wt_hi/Wt_lo [N,K] bf16 ------------
__global__ __launch_bounds__(256) void k_split_t(const float* __restrict__ W,
                                                 unsigned short* __restrict__ Th,
                                                 unsigned short* __restrict__ Tl,
                                                 int K, int N) {
  __shared__ float tile[32][33];
  int k0 = blockIdx.y * 32, n0 = blockIdx.x * 32;
  int t = threadIdx.x;
  int rr = t >> 3, cc = (t & 7) * 4;
  float4 v = *reinterpret_cast<const float4*>(&W[(size_t)(k0 + rr) * N + n0 + cc]);
  tile[rr][cc + 0] = v.x; tile[rr][cc + 1] = v.y; tile[rr][cc + 2] = v.z; tile[rr][cc + 3] = v.w;
  __syncthreads();
  // write row n = n0+rr, k cols k0+cc..+3
  ushort4 h, l;
  float f;
  f = tile[cc + 0][rr]; h.x = f2bf(f); l.x = f2bf(f - bf2f(h.x));
  f = tile[cc + 1][rr]; h.y = f2bf(f); l.y = f2bf(f - bf2f(h.y));
  f = tile[cc + 2][rr]; h.z = f2bf(f); l.z = f2bf(f - bf2f(h.z));
  f = tile[cc + 3][rr]; h.w = f2bf(f); l.w = f2bf(f - bf2f(h.w));
  size_t o = (size_t)(n0 + rr) * K + k0 + cc;
  *reinterpret_cast<ushort4*>(&Th[o]) = h;
  *reinterpret_cast<ushort4*>(&Tl[o]) = l;
}

// ---------------- split-bf16 MFMA GEMM: C[M,N] = (Ah+Al)[M,K] @ (Bh+Bl)[N,K]^T -------
// 128x128 tile, BK=32, 4 waves, 16x16x32 bf16 MFMA, 3-term split product.
__global__ __launch_bounds__(256) void k_gemm_mfma(const unsigned short* __restrict__ Ah,
                                                   const unsigned short* __restrict__ Al,
                                                   const unsigned short* __restrict__ Bh,
                                                   const unsigned short* __restrict__ Bl,
                                                   float* __restrict__ C, int M, int N, int K) {
  __shared__ unsigned short sAh[128 * 32], sAl[128 * 32], sBh[128 * 32], sBl[128 * 32];
  const int tid = threadIdx.x;
  const int lane = tid & 63, wv = tid >> 6;
  const int row0 = blockIdx.y * 128, col0 = blockIdx.x * 128;
  const int mBase = (wv >> 1) * 64, nBase = (wv & 1) * 64;
  const int lane15 = lane & 15;

  f32x4 acc[4][4];
#pragma unroll
  for (int m = 0; m < 4; ++m)
#pragma unroll
    for (int n = 0; n < 4; ++n) acc[m][n] = (f32x4){0.f, 0.f, 0.f, 0.f};

  // staging geometry: linear LDS dest, inverse-swizzled global source.
  // 16B unit swizzle within a 64B row: u ^= (r&3)^((r>>2)&3)  (involution)
  int rS[2], cS[2], dS[2];
#pragma unroll
  for (int c = 0; c < 2; ++c) {
    int p = c * 4096 + tid * 16;           // byte pos in 8KB tile
    int r = p >> 6, u = (p >> 4) & 3;
    int f = (r & 3) ^ ((r >> 2) & 3);
    rS[c] = r; cS[c] = (u ^ f) * 8; dS[c] = c * 2048 + tid * 8;   // ushort offsets
  }
  // read-side swizzle (depends only on lane&15 since frag rows are 16-aligned)
  const int fR = (lane & 3) ^ ((lane >> 2) & 3);
  const int uprime = (((lane >> 4) ^ fR) * 8);

  for (int k0 = 0; k0 < K; k0 += 32) {
#pragma unroll
    for (int c = 0; c < 2; ++c) {
      size_t ga = (size_t)(row0 + rS[c]) * K + k0 + cS[c];
      size_t gb = (size_t)(col0 + rS[c]) * K + k0 + cS[c];
      __builtin_amdgcn_global_load_lds((const __attribute__((address_space(1))) void*)(Ah + ga),
                                       (__attribute__((address_space(3))) void*)(sAh + dS[c]), 16, 0, 0);
      __builtin_amdgcn_global_load_lds((const __attribute__((address_space(1))) void*)(Al + ga),
                                       (__attribute__((address_space(3))) void*)(sAl + dS[c]), 16, 0, 0);
      __builtin_amdgcn_global_load_lds((const __attribute__((address_space(1))) void*)(Bh + gb),
                                       (__attribute__((address_space(3))) void*)(sBh + dS[c]), 16, 0, 0);
      __builtin_amdgcn_global_load_lds((const __attribute__((address_space(1))) void*)(Bl + gb),
                                       (__attribute__((address_space(3))) void*)(sBl + dS[c]), 16, 0, 0);
    }
    __syncthreads();

    short8 ah[4], al[4], bh[4], bl[4];
#pragma unroll
    for (int m = 0; m < 4; ++m) {
      int ia = (mBase + m * 16 + lane15) * 32 + uprime;
      ah[m] = *reinterpret_cast<const short8*>(sAh + ia);
      al[m] = *reinterpret_cast<const short8*>(sAl + ia);
      int ib = (nBase + m * 16 + lane15) * 32 + uprime;
      bh[m] = *reinterpret_cast<const short8*>(sBh + ib);
      bl[m] = *reinterpret_cast<const short8*>(sBl + ib);
    }
#pragma unroll
    for (int m = 0; m < 4; ++m)
#pragma unroll
      for (int n = 0; n < 4; ++n) {
        acc[m][n] = __builtin_amdgcn_mfma_f32_16x16x32_bf16(ah[m], bh[n], acc[m][n], 0, 0, 0);
        acc[m][n] = __builtin_amdgcn_mfma_f32_16x16x32_bf16(ah[m], bl[n], acc[m][n], 0, 0, 0);
        acc[m][n] = __builtin_amdgcn_mfma_f32_16x16x32_bf16(al[m], bh[n], acc[m][n], 0, 0, 0);
      }
    __syncthreads();
  }

  // C/D layout: col = lane&15, row = (lane>>4)*4 + j  [verified m89]
#pragma unroll
  for (int m = 0; m < 4; ++m) {
    int rr = row0 + mBase + m * 16 + (lane >> 4) * 4;
#pragma unroll
    for (int n = 0; n < 4; ++n) {
      int cc = col0 + nBase + n * 16 + lane15;
#pragma unroll
      for (int j = 0; j < 4; ++j)
        C[(size_t)(rr + j) * N + cc] = acc[m][n][j];
    }
  }
}

// ---------------- attention coefficients: alpha_src/dst[n,h] = dot(h[n,h,:], a[h,:]) ----
__global__ __launch_bounds__(256) void k_alpha4(const float* __restrict__ h, const float* __restrict__ a_s,
                                                const float* __restrict__ a_d,
                                                float* __restrict__ asrc, float* __restrict__ adst) {
  int wid = (blockIdx.x * 256 + threadIdx.x) >> 6;   // node*4 + head
  int lane = threadIdx.x & 63;
  int node = wid >> 2, hd = wid & 3;
  float4 hv = *reinterpret_cast<const float4*>(&h[(size_t)node * FDIM + hd * HID + lane * 4]);
  float4 sv = *reinterpret_cast<const float4*>(&a_s[hd * HID + lane * 4]);
  float4 dv = *reinterpret_cast<const float4*>(&a_d[hd * HID + lane * 4]);
  float ps = hv.x * sv.x + hv.y * sv.y + hv.z * sv.z + hv.w * sv.w;
  float pd = hv.x * dv.x + hv.y * dv.y + hv.z * dv.z + hv.w * dv.w;
  for (int off = 32; off > 0; off >>= 1) {
    ps += __shfl_down(ps, off);
    pd += __shfl_down(pd, off);
  }
  if (lane == 0) { asrc[wid] = ps; adst[wid] = pd; }
}

// ---------------- GAT aggregation, H=4, F=256: one wave per (node, head) -------------
// Output written as bf16 hi/lo split (feeds the next MFMA GEMM).
__global__ __launch_bounds__(256) void k_agg4(const float* __restrict__ h, const float* __restrict__ asrc,
                                              const float* __restrict__ adst, const int* __restrict__ row_ptr,
                                              const int* __restrict__ csr_src, const float* __restrict__ bias,
                                              unsigned short* __restrict__ outHi,
                                              unsigned short* __restrict__ outLo) {
  int wid = (blockIdx.x * 256 + threadIdx.x) >> 6;
  int lane = threadIdx.x & 63;
  int node = wid >> 2, hd = wid & 3;
  int beg = row_ptr[node], end = row_ptr[node + 1];
  float adn = adst[wid];
  float m = -INFINITY, s = 0.f;
  float ax = 0.f, ay = 0.f, az = 0.f, aw = 0.f;
  for (int e = beg; e < end; ++e) {
    int sidx = csr_src[e];
    float a = asrc[sidx * 4 + hd] + adn;
    a = a > 0.f ? a : NEG_SLOPE * a;            // leaky_relu
    float nm = fmaxf(m, a);
    float sc = __expf(m - nm);                  // exp(-inf)=0 on first edge
    float p  = __expf(a - nm);
    m = nm;
    s = s * sc + p;
    float4 hv = *reinterpret_cast<const float4*>(&h[(size_t)sidx * FDIM + hd * HID + lane * 4]);
    ax = ax * sc + p * hv.x;
    ay = ay * sc + p * hv.y;
    az = az * sc + p * hv.z;
    aw = aw * sc + p * hv.w;
  }
  float inv = 1.f / s;
  int fo = hd * HID + lane * 4;
  float4 bv = *reinterpret_cast<const float4*>(&bias[fo]);
  float4 o;
  o.x = ax * inv + bv.x; o.y = ay * inv + bv.y; o.z = az * inv + bv.z; o.w = aw * inv + bv.w;
  // ELU
  o.x = o.x > 0.f ? o.x : __expf(o.x) - 1.f;
  o.y = o.y > 0.f ? o.y : __expf(o.y) - 1.f;
  o.z = o.z > 0.f ? o.z : __expf(o.z) - 1.f;
  o.w = o.w > 0.f ? o.w : __expf(o.w) - 1.f;
  ushort4 hh, ll;
  hh.x = f2bf(o.x); ll.x = f2bf(o.x - bf2f(hh.x));
  hh.y = f2bf(o.y); ll.y = f2bf(o.y - bf2f(hh.y));
  hh.z = f2bf(o.z); ll.z = f2bf(o.z - bf2f(hh.z));
  hh.w = f2bf(o.w); ll.w = f2bf(o.w - bf2f(hh.w));
  size_t oo = (size_t)node * FDIM + fo;
  *reinterpret_cast<ushort4*>(&outHi[oo]) = hh;
  *reinterpret_cast<ushort4*>(&outLo[oo]) = ll;
}

// ---------------- layer-3 GEMM: [N,1024](hi/lo bf16) @ [1024,16]f32, B in LDS --------
__global__ __launch_bounds__(256) void k_gemm_n16(const unsigned short* __restrict__ Ah,
                                                  const unsigned short* __restrict__ Al,
                                                  const float* __restrict__ B,
                                                  float* __restrict__ C, int K) {
  __shared__ float Bs[16384];                   // 1024 x 16 = full B
  int tid = threadIdx.x;
  for (int idx = tid * 4; idx < K * 16; idx += 1024)
    *reinterpret_cast<float4*>(&Bs[idx]) = *reinterpret_cast<const float4*>(&B[idx]);
  __syncthreads();
  int row = blockIdx.x * 16 + (tid >> 4);
  int col = tid & 15;
  const unsigned short* ArH = &Ah[(size_t)row * K];
  const unsigned short* ArL = &Al[(size_t)row * K];
  float acc = 0.f;
  for (int k = 0; k < K; k += 4) {
    ushort4 hv = *reinterpret_cast<const ushort4*>(&ArH[k]);
    ushort4 lv = *reinterpret_cast<const ushort4*>(&ArL[k]);
    float a0 = bf2f(hv.x) + bf2f(lv.x);
    float a1 = bf2f(hv.y) + bf2f(lv.y);
    float a2 = bf2f(hv.z) + bf2f(lv.z);
    float a3 = bf2f(hv.w) + bf2f(lv.w);
    acc = fmaf(a0, Bs[(k + 0) * 16 + col],
          fmaf(a1, Bs[(k + 1) * 16 + col],
          fmaf(a2, Bs[(k + 2) * 16 + col],
          fmaf(a3, Bs[(k + 3) * 16 + col], acc))));
  }
  C[(size_t)row * 16 + col] = acc;
}

__global__ void k_alpha1(const float* __restrict__ h3, const float* __restrict__ a_s,
                         const float* __restrict__ a_d, float* __restrict__ asrc,
                         float* __restrict__ adst) {
  int i = blockIdx.x * 256 + threadIdx.x;
  if (i >= N_NODES) return;
  float ps = 0.f, pd = 0.f;
#pragma unroll
  for (int j = 0; j < EMB; ++j) {
    float v = h3[i * EMB + j];
    ps += v * a_s[j];
    pd += v * a_d[j];
  }
  asrc[i] = ps;
  adst[i] = pd;
}

// layer-3 aggregation: 16 threads per node (one per feature), no ELU, writes z
__global__ __launch_bounds__(256) void k_agg1(const float* __restrict__ h3, const float* __restrict__ asrc,
                                              const float* __restrict__ adst, const int* __restrict__ row_ptr,
                                              const int* __restrict__ csr_src, const float* __restrict__ bias,
                                              float* __restrict__ z) {
  int idx = blockIdx.x * 256 + threadIdx.x;
  int node = idx >> 4, f = idx & 15;
  if (node >= N_NODES) return;
  int beg = row_ptr[node], end = row_ptr[node + 1];
  float adn = adst[node];
  float m = -INFINITY, s = 0.f, acc = 0.f;
  for (int e = beg; e < end; ++e) {
    int sidx = csr_src[e];
    float a = asrc[sidx] + adn;
    a = a > 0.f ? a : NEG_SLOPE * a;
    float nm = fmaxf(m, a);
    float sc = __expf(m - nm);
    float p  = __expf(a - nm);
    m = nm;
    s = s * sc + p;
    acc = acc * sc + p * h3[sidx * EMB + f];
  }
  z[node * EMB + f] = acc / s + bias[f];
}

// ---------------- adjacency reconstruction: sigmoid(z @ z^T), 64x64 tiles -----------
__global__ __launch_bounds__(256) void k_adj(const float* __restrict__ z, float* __restrict__ adj) {
  __shared__ float Zr[16][64];   // k-major
  __shared__ float Zc[16][64];
  int tid = threadIdx.x;
  int r0 = blockIdx.y * 64, c0 = blockIdx.x * 64;
  {
    int m = tid >> 2, kk = (tid & 3) * 4;
    float4 v = *reinterpret_cast<const float4*>(&z[(size_t)(r0 + m) * EMB + kk]);
    Zr[kk + 0][m] = v.x; Zr[kk + 1][m] = v.y; Zr[kk + 2][m] = v.z; Zr[kk + 3][m] = v.w;
    float4 w = *reinterpret_cast<const float4*>(&z[(size_t)(c0 + m) * EMB + kk]);
    Zc[kk + 0][m] = w.x; Zc[kk + 1][m] = w.y; Zc[kk + 2][m] = w.z; Zc[kk + 3][m] = w.w;
  }
  __syncthreads();
  int tx = tid & 15, ty = tid >> 4;
  float acc[4][4] = {};
#pragma unroll
  for (int k = 0; k < 16; ++k) {
    float a[4], b[4];
#pragma unroll
    for (int i = 0; i < 4; ++i) a[i] = Zr[k][ty * 4 + i];
#pragma unroll
    for (int j = 0; j < 4; ++j) b[j] = Zc[k][tx * 4 + j];
#pragma unroll
    for (int i = 0; i < 4; ++i)
#pragma unroll
      for (int j = 0; j < 4; ++j) acc[i][j] = fmaf(a[i], b[j], acc[i][j]);
  }
  for (int i = 0; i < 4; ++i) {
    float4 o;
    o.x = 1.f / (1.f + __expf(-acc[i][0]));
    o.y = 1.f / (1.f + __expf(-acc[i][1]));
    o.z = 1.f / (1.f + __expf(-acc[i][2]));
    o.w = 1.f / (1.f + __expf(-acc[i][3]));
    *reinterpret_cast<float4*>(&adj[(size_t)(r0 + ty * 4 + i) * N_NODES + c0 + tx * 4]) = o;
  }
}

// ---------------- Student-t soft assignment, K=2 ------------------------------------
__global__ void k_q(const float* __restrict__ z, const float* __restrict__ centers,
                    float* __restrict__ q) {
  int i = blockIdx.x * 256 + threadIdx.x;
  if (i >= N_NODES) return;
  float zz[EMB];
#pragma unroll
  for (int j = 0; j < EMB; ++j) zz[j] = z[i * EMB + j];
  float q0, q1;
  {
    float d2 = 0.f;
#pragma unroll
    for (int j = 0; j < EMB; ++j) { float d = zz[j] - centers[j]; d2 = fmaf(d, d, d2); }
    q0 = 1.f / (1.f + d2);
  }
  {
    float d2 = 0.f;
#pragma unroll
    for (int j = 0; j < EMB; ++j) { float d = zz[j] - centers[EMB + j]; d2 = fmaf(d, d, d2); }
    q1 = 1.f / (1.f + d2);
  }
  float inv = 1.f / (q0 + q1);
  q[i * 2 + 0] = q0 * inv;
  q[i * 2 + 1] = q1 * inv;
}

// ====================================================================================
extern "C" void kernel_launch(void* const* d_in, const int* in_sizes, int n_in,
                              void* d_out, int out_size, void* d_ws, size_t ws_size,
                              hipStream_t stream) {
  const float* x   = (const float*)d_in[0];
  const int*   ei  = (const int*)d_in[1];
  const float* W1  = (const float*)d_in[2];
  const float* as1 = (const float*)d_in[3];
  const float* ad1 = (const float*)d_in[4];
  const float* b1  = (const float*)d_in[5];
  const float* W2  = (const float*)d_in[6];
  const float* as2 = (const float*)d_in[7];
  const float* ad2 = (const float*)d_in[8];
  const float* b2  = (const float*)d_in[9];
  const float* W3  = (const float*)d_in[10];
  const float* as3 = (const float*)d_in[11];
  const float* ad3 = (const float*)d_in[12];
  const float* b3  = (const float*)d_in[13];
  const float* centers = (const float*)d_in[14];
  float* out = (float*)d_out;

  char* ws = (char*)d_ws;
  size_t off = 0;
  auto alloc = [&](size_t bytes) { void* p = ws + off; off = (off + bytes + 255) & ~(size_t)255; return p; };
  int* cnt       = (int*)alloc((size_t)N_NODES * 4);
  int* cur       = (int*)alloc((size_t)N_NODES * 4);
  int* row_ptr   = (int*)alloc((size_t)(N_NODES + 1) * 4);
  int* csr_src   = (int*)alloc((size_t)EP_EDGES * 4);
  float* asrcA   = (float*)alloc((size_t)N_NODES * HEADS * 4);
  float* adstA   = (float*)alloc((size_t)N_NODES * HEADS * 4);
  float* asrc3   = (float*)alloc((size_t)N_NODES * 4);
  float* adst3   = (float*)alloc((size_t)N_NODES * 4);
  float* bufH    = (float*)alloc((size_t)N_NODES * FDIM * 4);       // f32 GEMM output
  unsigned short* aggHi = (unsigned short*)alloc((size_t)N_NODES * FDIM * 2);
  unsigned short* aggLo = (unsigned short*)alloc((size_t)N_NODES * FDIM * 2);
  unsigned short* xHi   = (unsigned short*)alloc((size_t)N_NODES * 128 * 2);
  unsigned short* xLo   = (unsigned short*)alloc((size_t)N_NODES * 128 * 2);
  unsigned short* w1tHi = (unsigned short*)alloc((size_t)FDIM * 128 * 2);
  unsigned short* w1tLo = (unsigned short*)alloc((size_t)FDIM * 128 * 2);
  unsigned short* w2tHi = (unsigned short*)alloc((size_t)FDIM * FDIM * 2);
  unsigned short* w2tLo = (unsigned short*)alloc((size_t)FDIM * FDIM * 2);
  float* bufZ    = (float*)alloc((size_t)N_NODES * EMB * 4);

  hipMemsetAsync(cnt, 0, (size_t)N_NODES * 4, stream);
  hipMemsetAsync(cur, 0, (size_t)N_NODES * 4, stream);

  const int ep_blocks = (EP_EDGES + 255) / 256;
  k_hist<<<dim3(ep_blocks), dim3(256), 0, stream>>>(ei, cnt);
  k_scan<<<dim3(1), dim3(1024), 0, stream>>>(cnt, row_ptr);
  k_scatter<<<dim3(ep_blocks), dim3(256), 0, stream>>>(ei, row_ptr, cur, csr_src);

  // ---- weight/input splits (run every launch; cheap)
  k_split<<<dim3((N_NODES * 128 / 4 + 255) / 256), dim3(256), 0, stream>>>(x, xHi, xLo, N_NODES * 128 / 4);
  k_split_t<<<dim3(FDIM / 32, 128 / 32), dim3(256), 0, stream>>>(W1, w1tHi, w1tLo, 128, FDIM);
  k_split_t<<<dim3(FDIM / 32, FDIM / 32), dim3(256), 0, stream>>>(W2, w2tHi, w2tLo, FDIM, FDIM);

  // ---- layer 1: 128 -> 4x256
  k_gemm_mfma<<<dim3(FDIM / 128, N_NODES / 128), dim3(256), 0, stream>>>(
      xHi, xLo, w1tHi, w1tLo, bufH, N_NODES, FDIM, 128);
  k_alpha4<<<dim3(N_NODES), dim3(256), 0, stream>>>(bufH, as1, ad1, asrcA, adstA);
  k_agg4<<<dim3(N_NODES), dim3(256), 0, stream>>>(bufH, asrcA, adstA, row_ptr, csr_src, b1, aggHi, aggLo);

  // ---- layer 2: 1024 -> 4x256
  k_gemm_mfma<<<dim3(FDIM / 128, N_NODES / 128), dim3(256), 0, stream>>>(
      aggHi, aggLo, w2tHi, w2tLo, bufH, N_NODES, FDIM, FDIM);
  k_alpha4<<<dim3(N_NODES), dim3(256), 0, stream>>>(bufH, as2, ad2, asrcA, adstA);
  k_agg4<<<dim3(N_NODES), dim3(256), 0, stream>>>(bufH, asrcA, adstA, row_ptr, csr_src, b2, aggHi, aggLo);

  // ---- layer 3: 1024 -> 16, 1 head, no ELU; z written straight into d_out
  k_gemm_n16<<<dim3(N_NODES / 16), dim3(256), 0, stream>>>(aggHi, aggLo, W3, bufZ, FDIM);
  k_alpha1<<<dim3((N_NODES + 255) / 256), dim3(256), 0, stream>>>(bufZ, as3, ad3, asrc3, adst3);
  k_agg1<<<dim3(N_NODES * EMB / 256), dim3(256), 0, stream>>>(bufZ, asrc3, adst3, row_ptr, csr_src, b3, out);

  // ---- decoder
  float* adj = out + (size_t)N_NODES * EMB;
  float* q   = adj + (size_t)N_NODES * N_NODES;
  k_adj<<<dim3(N_NODES / 64, N_NODES / 64), dim3(256), 0, stream>>>(out, adj);
  k_q<<<dim3((N_NODES + 255) / 256), dim3(256), 0, stream>>>(out, centers, q);
}

// Round 3
// 571.663 us; speedup vs baseline: 1.5086x; 1.1182x over previous
//
#include <hip/hip_runtime.h>
#include <hip/hip_bf16.h>
#include <math.h>

#define N_NODES 12288
#define N_EDGES 196608
#define EP_EDGES (N_EDGES + N_NODES)   // 208896 edges incl. self loops
#define HEADS 4
#define HID 256
#define FDIM 1024                      // HEADS*HID
#define EMB 16
#define NEG_SLOPE 0.2f

typedef __attribute__((ext_vector_type(8))) short short8;
typedef __attribute__((ext_vector_type(4))) float f32x4;

// bf16 helpers (RNE)
__device__ __forceinline__ unsigned short f2bf(float f) {
  unsigned int u = __float_as_uint(f);
  u = (u + 0x7FFFu + ((u >> 16) & 1u)) >> 16;
  return (unsigned short)u;
}
__device__ __forceinline__ float bf2f(unsigned short h) {
  return __uint_as_float(((unsigned int)h) << 16);
}

// ---------------- CSR build (dst-sorted, reused for all 3 layers) ----------------
__global__ void k_hist(const int* __restrict__ ei, int* __restrict__ cnt) {
  int i = blockIdx.x * 256 + threadIdx.x;
  if (i >= EP_EDGES) return;
  int d = (i < N_EDGES) ? ei[N_EDGES + i] : (i - N_EDGES);
  atomicAdd(&cnt[d], 1);
}

// parallel scan: (1) per-block exclusive scan + block sums
__global__ __launch_bounds__(1024) void k_scan1(const int* __restrict__ cnt,
                                                int* __restrict__ row_ptr,
                                                int* __restrict__ bsum) {
  __shared__ int sd[1024];
  int tid = threadIdx.x;
  int gid = blockIdx.x * 1024 + tid;
  int v = cnt[gid];
  sd[tid] = v;
  __syncthreads();
  for (int d = 1; d < 1024; d <<= 1) {
    int t = (tid >= d) ? sd[tid - d] : 0;
    __syncthreads();
    sd[tid] += t;
    __syncthreads();
  }
  row_ptr[gid] = sd[tid] - v;          // block-local exclusive
  if (tid == 1023) bsum[blockIdx.x] = sd[1023];
}

// (2) tiny serial scan of block sums
__global__ void k_scan2(int* __restrict__ bsum, int* __restrict__ boff,
                        int nb, int* __restrict__ row_ptr_last) {
  if (threadIdx.x == 0 && blockIdx.x == 0) {
    int acc = 0;
    for (int b = 0; b < nb; ++b) { boff[b] = acc; acc += bsum[b]; }
    *row_ptr_last = acc;
  }
}

// (3) add block offsets
__global__ void k_scan3(int* __restrict__ row_ptr, const int* __restrict__ boff) {
  int gid = blockIdx.x * 256 + threadIdx.x;
  row_ptr[gid] += boff[gid >> 10];
}

__global__ void k_scatter(const int* __restrict__ ei, const int* __restrict__ row_ptr,
                          int* __restrict__ cur, int* __restrict__ csr_src) {
  int i = blockIdx.x * 256 + threadIdx.x;
  if (i >= EP_EDGES) return;
  int s, d;
  if (i < N_EDGES) { s = ei[i]; d = ei[N_EDGES + i]; }
  else             { s = i - N_EDGES; d = s; }
  int pos = row_ptr[d] + atomicAdd(&cur[d], 1);
  csr_src[pos] = s;
}

// ---------------- fp32 -> bf16 hi/lo split (elementwise, no transpose) ---------------
__global__ void k_split(const float* __restrict__ in, unsigned short* __restrict__ hi,
                        unsigned short* __restrict__ lo, int n4) {
  int i = blockIdx.x * 256 + threadIdx.x;
  if (i >= n4) return;
  float4 v = *reinterpret_cast<const float4*>(&in[(size_t)i * 4]);
  ushort4 h, l;
  h.x = f2bf(v.x); l.x = f2bf(v.x - bf2f(h.x));
  h.y = f2bf(v.y); l.y = f2bf(v.y - bf2f(h.y));
  h.z = f2bf(v.z); l.z = f2bf(v.z - bf2f(h.z));
  h.w = f2bf(v.w); l.w = f2bf(v.w - bf2f(h.w));
  *reinterpret_cast<ushort4*>(&hi[(size_t)i * 4]) = h;
  *reinterpret_cast<ushort4*>(&lo[(size_t)i * 4]) = l;
}

// ---------------- transpose + split: W[K,N] f32 -> Wt_hi/Wt_lo [N,K] bf16 ------------
__global__ __launch_bounds__(256) void k_split_t(const float* __restrict__ W,
                                                 unsigned short* __restrict__ Th,
                                                 unsigned short* __restrict__ Tl,
                                                 int K, int N) {
  __shared__ float tile[32][33];
  int k0 = blockIdx.y * 32, n0 = blockIdx.x * 32;
  int t = threadIdx.x;
  int rr = t >> 3, cc = (t & 7) * 4;
  float4 v = *reinterpret_cast<const float4*>(&W[(size_t)(k0 + rr) * N + n0 + cc]);
  tile[rr][cc + 0] = v.x; tile[rr][cc + 1] = v.y; tile[rr][cc + 2] = v.z; tile[rr][cc + 3] = v.w;
  __syncthreads();
  ushort4 h, l;
  float f;
  f = tile[cc + 0][rr]; h.x = f2bf(f); l.x = f2bf(f - bf2f(h.x));
  f = tile[cc + 1][rr]; h.y = f2bf(f); l.y = f2bf(f - bf2f(h.y));
  f = tile[cc + 2][rr]; h.z = f2bf(f); l.z = f2bf(f - bf2f(h.z));
  f = tile[cc + 3][rr]; h.w = f2bf(f); l.w = f2bf(f - bf2f(h.w));
  size_t o = (size_t)(n0 + rr) * K + k0 + cc;
  *reinterpret_cast<ushort4*>(&Th[o]) = h;
  *reinterpret_cast<ushort4*>(&Tl[o]) = l;
}

// ---------------- split-bf16 MFMA GEMM: Cbf[M,N] = (Ah+Al)[M,K] @ (Bh+Bl)[N,K]^T -----
// 128x128 tile, BK=32, 4 waves, 16x16x32 bf16 MFMA, 3-term split product; bf16 output.
__global__ __launch_bounds__(256) void k_gemm_mfma(const unsigned short* __restrict__ Ah,
                                                   const unsigned short* __restrict__ Al,
                                                   const unsigned short* __restrict__ Bh,
                                                   const unsigned short* __restrict__ Bl,
                                                   unsigned short* __restrict__ Cbf,
                                                   int M, int N, int K) {
  __shared__ unsigned short sAh[128 * 32], sAl[128 * 32], sBh[128 * 32], sBl[128 * 32];
  const int tid = threadIdx.x;
  const int lane = tid & 63, wv = tid >> 6;
  const int row0 = blockIdx.y * 128, col0 = blockIdx.x * 128;
  const int mBase = (wv >> 1) * 64, nBase = (wv & 1) * 64;
  const int lane15 = lane & 15;

  f32x4 acc[4][4];
#pragma unroll
  for (int m = 0; m < 4; ++m)
#pragma unroll
    for (int n = 0; n < 4; ++n) acc[m][n] = (f32x4){0.f, 0.f, 0.f, 0.f};

  // staging geometry: linear LDS dest, inverse-swizzled global source.
  // 16B unit swizzle within a 64B row: u ^= (r&3)^((r>>2)&3)  (involution)
  int rS[2], cS[2], dS[2];
#pragma unroll
  for (int c = 0; c < 2; ++c) {
    int p = c * 4096 + tid * 16;           // byte pos in 8KB tile
    int r = p >> 6, u = (p >> 4) & 3;
    int f = (r & 3) ^ ((r >> 2) & 3);
    rS[c] = r; cS[c] = (u ^ f) * 8; dS[c] = c * 2048 + tid * 8;   // ushort offsets
  }
  const int fR = (lane & 3) ^ ((lane >> 2) & 3);
  const int uprime = (((lane >> 4) ^ fR) * 8);

  for (int k0 = 0; k0 < K; k0 += 32) {
#pragma unroll
    for (int c = 0; c < 2; ++c) {
      size_t ga = (size_t)(row0 + rS[c]) * K + k0 + cS[c];
      size_t gb = (size_t)(col0 + rS[c]) * K + k0 + cS[c];
      __builtin_amdgcn_global_load_lds((const __attribute__((address_space(1))) void*)(Ah + ga),
                                       (__attribute__((address_space(3))) void*)(sAh + dS[c]), 16, 0, 0);
      __builtin_amdgcn_global_load_lds((const __attribute__((address_space(1))) void*)(Al + ga),
                                       (__attribute__((address_space(3))) void*)(sAl + dS[c]), 16, 0, 0);
      __builtin_amdgcn_global_load_lds((const __attribute__((address_space(1))) void*)(Bh + gb),
                                       (__attribute__((address_space(3))) void*)(sBh + dS[c]), 16, 0, 0);
      __builtin_amdgcn_global_load_lds((const __attribute__((address_space(1))) void*)(Bl + gb),
                                       (__attribute__((address_space(3))) void*)(sBl + dS[c]), 16, 0, 0);
    }
    __syncthreads();

    short8 ah[4], al[4], bh[4], bl[4];
#pragma unroll
    for (int m = 0; m < 4; ++m) {
      int ia = (mBase + m * 16 + lane15) * 32 + uprime;
      ah[m] = *reinterpret_cast<const short8*>(sAh + ia);
      al[m] = *reinterpret_cast<const short8*>(sAl + ia);
      int ib = (nBase + m * 16 + lane15) * 32 + uprime;
      bh[m] = *reinterpret_cast<const short8*>(sBh + ib);
      bl[m] = *reinterpret_cast<const short8*>(sBl + ib);
    }
#pragma unroll
    for (int m = 0; m < 4; ++m)
#pragma unroll
      for (int n = 0; n < 4; ++n) {
        acc[m][n] = __builtin_amdgcn_mfma_f32_16x16x32_bf16(ah[m], bh[n], acc[m][n], 0, 0, 0);
        acc[m][n] = __builtin_amdgcn_mfma_f32_16x16x32_bf16(ah[m], bl[n], acc[m][n], 0, 0, 0);
        acc[m][n] = __builtin_amdgcn_mfma_f32_16x16x32_bf16(al[m], bh[n], acc[m][n], 0, 0, 0);
      }
    __syncthreads();
  }

  // C/D layout: col = lane&15, row = (lane>>4)*4 + j  [verified m89]
#pragma unroll
  for (int m = 0; m < 4; ++m) {
    int rr = row0 + mBase + m * 16 + (lane >> 4) * 4;
#pragma unroll
    for (int n = 0; n < 4; ++n) {
      int cc = col0 + nBase + n * 16 + lane15;
#pragma unroll
      for (int j = 0; j < 4; ++j)
        Cbf[(size_t)(rr + j) * N + cc] = f2bf(acc[m][n][j]);
    }
  }
}

// ---------------- attention coefficients from bf16 h ---------------------------------
__global__ __launch_bounds__(256) void k_alpha4(const unsigned short* __restrict__ h,
                                                const float* __restrict__ a_s,
                                                const float* __restrict__ a_d,
                                                float* __restrict__ asrc, float* __restrict__ adst) {
  int wid = (blockIdx.x * 256 + threadIdx.x) >> 6;   // node*4 + head
  int lane = threadIdx.x & 63;
  int node = wid >> 2, hd = wid & 3;
  ushort4 hu = *reinterpret_cast<const ushort4*>(&h[(size_t)node * FDIM + hd * HID + lane * 4]);
  float4 sv = *reinterpret_cast<const float4*>(&a_s[hd * HID + lane * 4]);
  float4 dv = *reinterpret_cast<const float4*>(&a_d[hd * HID + lane * 4]);
  float h0 = bf2f(hu.x), h1 = bf2f(hu.y), h2 = bf2f(hu.z), h3 = bf2f(hu.w);
  float ps = h0 * sv.x + h1 * sv.y + h2 * sv.z + h3 * sv.w;
  float pd = h0 * dv.x + h1 * dv.y + h2 * dv.z + h3 * dv.w;
  for (int off = 32; off > 0; off >>= 1) {
    ps += __shfl_down(ps, off);
    pd += __shfl_down(pd, off);
  }
  if (lane == 0) { asrc[wid] = ps; adst[wid] = pd; }
}

// ---------------- GAT aggregation, H=4, F=256: one wave per (node, head) -------------
// bf16 h gather; output written as bf16 hi/lo split (feeds the next MFMA GEMM).
__global__ __launch_bounds__(256) void k_agg4(const unsigned short* __restrict__ h,
                                              const float* __restrict__ asrc,
                                              const float* __restrict__ adst, const int* __restrict__ row_ptr,
                                              const int* __restrict__ csr_src, const float* __restrict__ bias,
                                              unsigned short* __restrict__ outHi,
                                              unsigned short* __restrict__ outLo) {
  int wid = (blockIdx.x * 256 + threadIdx.x) >> 6;
  int lane = threadIdx.x & 63;
  int node = wid >> 2, hd = wid & 3;
  int beg = row_ptr[node], end = row_ptr[node + 1];
  float adn = adst[wid];
  float m = -INFINITY, s = 0.f;
  float ax = 0.f, ay = 0.f, az = 0.f, aw = 0.f;
  for (int e = beg; e < end; ++e) {
    int sidx = csr_src[e];
    float a = asrc[sidx * 4 + hd] + adn;
    a = a > 0.f ? a : NEG_SLOPE * a;            // leaky_relu
    float nm = fmaxf(m, a);
    float sc = __expf(m - nm);                  // exp(-inf)=0 on first edge
    float p  = __expf(a - nm);
    m = nm;
    s = s * sc + p;
    ushort4 hu = *reinterpret_cast<const ushort4*>(&h[(size_t)sidx * FDIM + hd * HID + lane * 4]);
    ax = ax * sc + p * bf2f(hu.x);
    ay = ay * sc + p * bf2f(hu.y);
    az = az * sc + p * bf2f(hu.z);
    aw = aw * sc + p * bf2f(hu.w);
  }
  float inv = 1.f / s;
  int fo = hd * HID + lane * 4;
  float4 bv = *reinterpret_cast<const float4*>(&bias[fo]);
  float4 o;
  o.x = ax * inv + bv.x; o.y = ay * inv + bv.y; o.z = az * inv + bv.z; o.w = aw * inv + bv.w;
  // ELU
  o.x = o.x > 0.f ? o.x : __expf(o.x) - 1.f;
  o.y = o.y > 0.f ? o.y : __expf(o.y) - 1.f;
  o.z = o.z > 0.f ? o.z : __expf(o.z) - 1.f;
  o.w = o.w > 0.f ? o.w : __expf(o.w) - 1.f;
  ushort4 hh, ll;
  hh.x = f2bf(o.x); ll.x = f2bf(o.x - bf2f(hh.x));
  hh.y = f2bf(o.y); ll.y = f2bf(o.y - bf2f(hh.y));
  hh.z = f2bf(o.z); ll.z = f2bf(o.z - bf2f(hh.z));
  hh.w = f2bf(o.w); ll.w = f2bf(o.w - bf2f(hh.w));
  size_t oo = (size_t)node * FDIM + fo;
  *reinterpret_cast<ushort4*>(&outHi[oo]) = hh;
  *reinterpret_cast<ushort4*>(&outLo[oo]) = ll;
}

// ---------------- layer-3 GEMM: [N,1024](hi/lo bf16) @ [1024,16]f32, B in LDS --------
__global__ __launch_bounds__(256) void k_gemm_n16(const unsigned short* __restrict__ Ah,
                                                  const unsigned short* __restrict__ Al,
                                                  const float* __restrict__ B,
                                                  float* __restrict__ C, int K) {
  __shared__ float Bs[16384];                   // 1024 x 16 = full B
  int tid = threadIdx.x;
  for (int idx = tid * 4; idx < K * 16; idx += 1024)
    *reinterpret_cast<float4*>(&Bs[idx]) = *reinterpret_cast<const float4*>(&B[idx]);
  __syncthreads();
  int row = blockIdx.x * 16 + (tid >> 4);
  int col = tid & 15;
  const unsigned short* ArH = &Ah[(size_t)row * K];
  const unsigned short* ArL = &Al[(size_t)row * K];
  float acc = 0.f;
  for (int k = 0; k < K; k += 4) {
    ushort4 hv = *reinterpret_cast<const ushort4*>(&ArH[k]);
    ushort4 lv = *reinterpret_cast<const ushort4*>(&ArL[k]);
    float a0 = bf2f(hv.x) + bf2f(lv.x);
    float a1 = bf2f(hv.y) + bf2f(lv.y);
    float a2 = bf2f(hv.z) + bf2f(lv.z);
    float a3 = bf2f(hv.w) + bf2f(lv.w);
    acc = fmaf(a0, Bs[(k + 0) * 16 + col],
          fmaf(a1, Bs[(k + 1) * 16 + col],
          fmaf(a2, Bs[(k + 2) * 16 + col],
          fmaf(a3, Bs[(k + 3) * 16 + col], acc))));
  }
  C[(size_t)row * 16 + col] = acc;
}

__global__ void k_alpha1(const float* __restrict__ h3, const float* __restrict__ a_s,
                         const float* __restrict__ a_d, float* __restrict__ asrc,
                         float* __restrict__ adst) {
  int i = blockIdx.x * 256 + threadIdx.x;
  if (i >= N_NODES) return;
  float ps = 0.f, pd = 0.f;
#pragma unroll
  for (int j = 0; j < EMB; ++j) {
    float v = h3[i * EMB + j];
    ps += v * a_s[j];
    pd += v * a_d[j];
  }
  asrc[i] = ps;
  adst[i] = pd;
}

// layer-3 aggregation: 16 threads per node (one per feature), no ELU, writes z
__global__ __launch_bounds__(256) void k_agg1(const float* __restrict__ h3, const float* __restrict__ asrc,
                                              const float* __restrict__ adst, const int* __restrict__ row_ptr,
                                              const int* __restrict__ csr_src, const float* __restrict__ bias,
                                              float* __restrict__ z) {
  int idx = blockIdx.x * 256 + threadIdx.x;
  int node = idx >> 4, f = idx & 15;
  if (node >= N_NODES) return;
  int beg = row_ptr[node], end = row_ptr[node + 1];
  float adn = adst[node];
  float m = -INFINITY, s = 0.f, acc = 0.f;
  for (int e = beg; e < end; ++e) {
    int sidx = csr_src[e];
    float a = asrc[sidx] + adn;
    a = a > 0.f ? a : NEG_SLOPE * a;
    float nm = fmaxf(m, a);
    float sc = __expf(m - nm);
    float p  = __expf(a - nm);
    m = nm;
    s = s * sc + p;
    acc = acc * sc + p * h3[sidx * EMB + f];
  }
  z[node * EMB + f] = acc / s + bias[f];
}

// ---------------- adjacency reconstruction: sigmoid(z @ z^T), 64x64 tiles -----------
__global__ __launch_bounds__(256) void k_adj(const float* __restrict__ z, float* __restrict__ adj) {
  __shared__ float Zr[16][64];   // k-major
  __shared__ float Zc[16][64];
  int tid = threadIdx.x;
  int r0 = blockIdx.y * 64, c0 = blockIdx.x * 64;
  {
    int m = tid >> 2, kk = (tid & 3) * 4;
    float4 v = *reinterpret_cast<const float4*>(&z[(size_t)(r0 + m) * EMB + kk]);
    Zr[kk + 0][m] = v.x; Zr[kk + 1][m] = v.y; Zr[kk + 2][m] = v.z; Zr[kk + 3][m] = v.w;
    float4 w = *reinterpret_cast<const float4*>(&z[(size_t)(c0 + m) * EMB + kk]);
    Zc[kk + 0][m] = w.x; Zc[kk + 1][m] = w.y; Zc[kk + 2][m] = w.z; Zc[kk + 3][m] = w.w;
  }
  __syncthreads();
  int tx = tid & 15, ty = tid >> 4;
  float acc[4][4] = {};
#pragma unroll
  for (int k = 0; k < 16; ++k) {
    float a[4], b[4];
#pragma unroll
    for (int i = 0; i < 4; ++i) a[i] = Zr[k][ty * 4 + i];
#pragma unroll
    for (int j = 0; j < 4; ++j) b[j] = Zc[k][tx * 4 + j];
#pragma unroll
    for (int i = 0; i < 4; ++i)
#pragma unroll
      for (int j = 0; j < 4; ++j) acc[i][j] = fmaf(a[i], b[j], acc[i][j]);
  }
  for (int i = 0; i < 4; ++i) {
    float4 o;
    o.x = 1.f / (1.f + __expf(-acc[i][0]));
    o.y = 1.f / (1.f + __expf(-acc[i][1]));
    o.z = 1.f / (1.f + __expf(-acc[i][2]));
    o.w = 1.f / (1.f + __expf(-acc[i][3]));
    *reinterpret_cast<float4*>(&adj[(size_t)(r0 + ty * 4 + i) * N_NODES + c0 + tx * 4]) = o;
  }
}

// ---------------- Student-t soft assignment, K=2 ------------------------------------
__global__ void k_q(const float* __restrict__ z, const float* __restrict__ centers,
                    float* __restrict__ q) {
  int i = blockIdx.x * 256 + threadIdx.x;
  if (i >= N_NODES) return;
  float zz[EMB];
#pragma unroll
  for (int j = 0; j < EMB; ++j) zz[j] = z[i * EMB + j];
  float q0, q1;
  {
    float d2 = 0.f;
#pragma unroll
    for (int j = 0; j < EMB; ++j) { float d = zz[j] - centers[j]; d2 = fmaf(d, d, d2); }
    q0 = 1.f / (1.f + d2);
  }
  {
    float d2 = 0.f;
#pragma unroll
    for (int j = 0; j < EMB; ++j) { float d = zz[j] - centers[EMB + j]; d2 = fmaf(d, d, d2); }
    q1 = 1.f / (1.f + d2);
  }
  float inv = 1.f / (q0 + q1);
  q[i * 2 + 0] = q0 * inv;
  q[i * 2 + 1] = q1 * inv;
}

// ====================================================================================
extern "C" void kernel_launch(void* const* d_in, const int* in_sizes, int n_in,
                              void* d_out, int out_size, void* d_ws, size_t ws_size,
                              hipStream_t stream) {
  const float* x   = (const float*)d_in[0];
  const int*   ei  = (const int*)d_in[1];
  const float* W1  = (const float*)d_in[2];
  const float* as1 = (const float*)d_in[3];
  const float* ad1 = (const float*)d_in[4];
  const float* b1  = (const float*)d_in[5];
  const float* W2  = (const float*)d_in[6];
  const float* as2 = (const float*)d_in[7];
  const float* ad2 = (const float*)d_in[8];
  const float* b2  = (const float*)d_in[9];
  const float* W3  = (const float*)d_in[10];
  const float* as3 = (const float*)d_in[11];
  const float* ad3 = (const float*)d_in[12];
  const float* b3  = (const float*)d_in[13];
  const float* centers = (const float*)d_in[14];
  float* out = (float*)d_out;

  char* ws = (char*)d_ws;
  size_t off = 0;
  auto alloc = [&](size_t bytes) { void* p = ws + off; off = (off + bytes + 255) & ~(size_t)255; return p; };
  int* cnt       = (int*)alloc((size_t)N_NODES * 4);
  int* cur       = (int*)alloc((size_t)N_NODES * 4);
  int* row_ptr   = (int*)alloc((size_t)(N_NODES + 1) * 4);
  int* bsum      = (int*)alloc(64 * 4);
  int* boff      = (int*)alloc(64 * 4);
  int* csr_src   = (int*)alloc((size_t)EP_EDGES * 4);
  float* asrcA   = (float*)alloc((size_t)N_NODES * HEADS * 4);
  float* adstA   = (float*)alloc((size_t)N_NODES * HEADS * 4);
  float* asrc3   = (float*)alloc((size_t)N_NODES * 4);
  float* adst3   = (float*)alloc((size_t)N_NODES * 4);
  unsigned short* hbf   = (unsigned short*)alloc((size_t)N_NODES * FDIM * 2);  // bf16 h
  unsigned short* aggHi = (unsigned short*)alloc((size_t)N_NODES * FDIM * 2);
  unsigned short* aggLo = (unsigned short*)alloc((size_t)N_NODES * FDIM * 2);
  unsigned short* xHi   = (unsigned short*)alloc((size_t)N_NODES * 128 * 2);
  unsigned short* xLo   = (unsigned short*)alloc((size_t)N_NODES * 128 * 2);
  unsigned short* w1tHi = (unsigned short*)alloc((size_t)FDIM * 128 * 2);
  unsigned short* w1tLo = (unsigned short*)alloc((size_t)FDIM * 128 * 2);
  unsigned short* w2tHi = (unsigned short*)alloc((size_t)FDIM * FDIM * 2);
  unsigned short* w2tLo = (unsigned short*)alloc((size_t)FDIM * FDIM * 2);
  float* bufZ    = (float*)alloc((size_t)N_NODES * EMB * 4);

  hipMemsetAsync(cnt, 0, (size_t)N_NODES * 4, stream);
  hipMemsetAsync(cur, 0, (size_t)N_NODES * 4, stream);

  const int ep_blocks = (EP_EDGES + 255) / 256;
  k_hist<<<dim3(ep_blocks), dim3(256), 0, stream>>>(ei, cnt);
  k_scan1<<<dim3(N_NODES / 1024), dim3(1024), 0, stream>>>(cnt, row_ptr, bsum);
  k_scan2<<<dim3(1), dim3(64), 0, stream>>>(bsum, boff, N_NODES / 1024, row_ptr + N_NODES);
  k_scan3<<<dim3(N_NODES / 256), dim3(256), 0, stream>>>(row_ptr, boff);
  k_scatter<<<dim3(ep_blocks), dim3(256), 0, stream>>>(ei, row_ptr, cur, csr_src);

  // ---- weight/input splits (run every launch; cheap)
  k_split<<<dim3((N_NODES * 128 / 4 + 255) / 256), dim3(256), 0, stream>>>(x, xHi, xLo, N_NODES * 128 / 4);
  k_split_t<<<dim3(FDIM / 32, 128 / 32), dim3(256), 0, stream>>>(W1, w1tHi, w1tLo, 128, FDIM);
  k_split_t<<<dim3(FDIM / 32, FDIM / 32), dim3(256), 0, stream>>>(W2, w2tHi, w2tLo, FDIM, FDIM);

  // ---- layer 1: 128 -> 4x256
  k_gemm_mfma<<<dim3(FDIM / 128, N_NODES / 128), dim3(256), 0, stream>>>(
      xHi, xLo, w1tHi, w1tLo, hbf, N_NODES, FDIM, 128);
  k_alpha4<<<dim3(N_NODES), dim3(256), 0, stream>>>(hbf, as1, ad1, asrcA, adstA);
  k_agg4<<<dim3(N_NODES), dim3(256), 0, stream>>>(hbf, asrcA, adstA, row_ptr, csr_src, b1, aggHi, aggLo);

  // ---- layer 2: 1024 -> 4x256
  k_gemm_mfma<<<dim3(FDIM / 128, N_NODES / 128), dim3(256), 0, stream>>>(
      aggHi, aggLo, w2tHi, w2tLo, hbf, N_NODES, FDIM, FDIM);
  k_alpha4<<<dim3(N_NODES), dim3(256), 0, stream>>>(hbf, as2, ad2, asrcA, adstA);
  k_agg4<<<dim3(N_NODES), dim3(256), 0, stream>>>(hbf, asrcA, adstA, row_ptr, csr_src, b2, aggHi, aggLo);

  // ---- layer 3: 1024 -> 16, 1 head, no ELU; z written straight into d_out
  k_gemm_n16<<<dim3(N_NODES / 16), dim3(256), 0, stream>>>(aggHi, aggLo, W3, bufZ, FDIM);
  k_alpha1<<<dim3((N_NODES + 255) / 256), dim3(256), 0, stream>>>(bufZ, as3, ad3, asrc3, adst3);
  k_agg1<<<dim3(N_NODES * EMB / 256), dim3(256), 0, stream>>>(bufZ, asrc3, adst3, row_ptr, csr_src, b3, out);

  // ---- decoder
  float* adj = out + (size_t)N_NODES * EMB;
  float* q   = adj + (size_t)N_NODES * N_NODES;
  k_adj<<<dim3(N_NODES / 64, N_NODES / 64), dim3(256), 0, stream>>>(out, adj);
  k_q<<<dim3((N_NODES + 255) / 256), dim3(256), 0, stream>>>(out, centers, q);
}